// Round 4
// baseline (222.546 us; speedup 1.0000x reference)
//
#include <hip/hip_runtime.h>

#define NUM_CLASSES 26
#define NCOUNT (3 * NUM_CLASSES)      // 78 logical counters
#define SUBS 8                        // LDS sub-histograms
#define SUBSTRIDE 83                  // words between subs (coprime w/ 32 banks)
#define LDSN (SUBS * SUBSTRIDE)       // 664 words
#define NREP 16                       // global replicas to cut atomic contention
#define REPSTRIDE 80                  // words between replicas
#define GC_WORDS (NREP * REPSTRIDE)   // 1280
#define DONE_IDX GC_WORDS             // gc[1280] = arrival counter
#define TPB 256

__global__ void sdl_zero(unsigned int* __restrict__ c) {
    for (int i = threadIdx.x; i < GC_WORDS + 1; i += TPB) c[i] = 0u;
}

// LDS index: sub*83 + hist*26 + cls  (classes spread across banks)
#define HIDX(hist, cls) (sub * SUBSTRIDE + (hist) * NUM_CLASSES + (cls))
#define PROC_PAIR(aa, bb)                                                   \
    do {                                                                    \
        atomicAdd(&h[HIDX(0, (aa).x)], 1u);                                 \
        atomicAdd(&h[HIDX(0, (aa).y)], 1u);                                 \
        atomicAdd(&h[HIDX(0, (aa).z)], 1u);                                 \
        atomicAdd(&h[HIDX(0, (aa).w)], 1u);                                 \
        atomicAdd(&h[HIDX(1, (bb).x)], 1u);                                 \
        atomicAdd(&h[HIDX(1, (bb).y)], 1u);                                 \
        atomicAdd(&h[HIDX(1, (bb).z)], 1u);                                 \
        atomicAdd(&h[HIDX(1, (bb).w)], 1u);                                 \
        if ((aa).x == (bb).x) atomicAdd(&h[HIDX(2, (aa).x)], 1u);           \
        if ((aa).y == (bb).y) atomicAdd(&h[HIDX(2, (aa).y)], 1u);           \
        if ((aa).z == (bb).z) atomicAdd(&h[HIDX(2, (aa).z)], 1u);           \
        if ((aa).w == (bb).w) atomicAdd(&h[HIDX(2, (aa).w)], 1u);           \
    } while (0)

__global__ __launch_bounds__(TPB) void sdl_hist(
    const int4* __restrict__ f4, const int4* __restrict__ m4,
    unsigned int* __restrict__ gc, float* __restrict__ out,
    int n4, int nfull) {
    __shared__ unsigned int h[LDSN];
    for (int i = threadIdx.x; i < LDSN; i += TPB) h[i] = 0u;
    __syncthreads();

    const int tid      = blockIdx.x * TPB + threadIdx.x;
    const int nthreads = gridDim.x * TPB;
    const int sub      = threadIdx.x & (SUBS - 1);

    // one-shot batch of 8 pairs per thread (round-2 structure: best measured codegen)
    for (int base = tid; base < nfull; base += nthreads * 8) {
        int4 a[8], b[8];
        #pragma unroll
        for (int k = 0; k < 8; ++k) a[k] = f4[base + k * nthreads];
        #pragma unroll
        for (int k = 0; k < 8; ++k) b[k] = m4[base + k * nthreads];
        #pragma unroll
        for (int k = 0; k < 8; ++k) {
            int4 aa = a[k], bb = b[k];
            PROC_PAIR(aa, bb);
        }
    }
    for (int i = nfull + tid; i < n4; i += nthreads) {   // generic tail (empty here)
        int4 aa = f4[i], bb = m4[i];
        PROC_PAIR(aa, bb);
    }

    __syncthreads();
    // flush to one of 16 replicas — contention per word: gridDim/16
    {
        unsigned int* rep = gc + (blockIdx.x & (NREP - 1)) * REPSTRIDE;
        for (int i = threadIdx.x; i < NCOUNT; i += TPB) {
            unsigned int v = 0;
            #pragma unroll
            for (int s2 = 0; s2 < SUBS; ++s2) v += h[s2 * SUBSTRIDE + i];
            if (v) atomicAdd(&rep[i], v);
        }
    }

    // last-block finalize
    __threadfence();
    __shared__ int is_last;
    if (threadIdx.x == 0) {
        unsigned int old = atomicAdd(&gc[DONE_IDX], 1u);
        is_last = (old == (unsigned int)(gridDim.x - 1)) ? 1 : 0;
    }
    __syncthreads();
    if (is_last) {
        __shared__ float vals[NCOUNT];
        if (threadIdx.x < NCOUNT) {
            unsigned int v = 0;
            for (int r = 0; r < NREP; ++r)
                v += atomicAdd(&gc[r * REPSTRIDE + threadIdx.x], 0u);  // coherent read
            vals[threadIdx.x] = (float)v;
        }
        __syncthreads();
        if (threadIdx.x == 0) {
            const float eps = 1e-5f;
            float ssum = 0.f;
            for (int c = 1; c < NUM_CLASSES; ++c) {
                float F = vals[c];
                float M = vals[NUM_CLASSES + c];
                float I = vals[2 * NUM_CLASSES + c];
                ssum += (2.f * I + eps) / (F + M + eps);
            }
            out[0] = 1.f - ssum / (float)(NUM_CLASSES - 1);
        }
    }
}

extern "C" void kernel_launch(void* const* d_in, const int* in_sizes, int n_in,
                              void* d_out, int out_size, void* d_ws, size_t ws_size,
                              hipStream_t stream) {
    const int* f = (const int*)d_in[0];
    const int* m = (const int*)d_in[1];
    unsigned int* gc = (unsigned int*)d_ws;
    float* out = (float*)d_out;

    int n  = in_sizes[0];         // 14,155,776 (divisible by 4)
    int n4 = n / 4;               // 3,538,944 int4-pairs

    sdl_zero<<<1, TPB, 0, stream>>>(gc);

    int blocks = n4 / (TPB * 8);  // 1728: each thread exactly 8 pairs
    if (blocks < 1) blocks = 1;
    if (blocks > 4096) blocks = 4096;
    int nthreads = blocks * TPB;
    int nfull = (n4 / (nthreads * 8)) * (nthreads * 8);

    sdl_hist<<<blocks, TPB, 0, stream>>>((const int4*)f, (const int4*)m,
                                         gc, out, n4, nfull);
}

// Round 5
// 31.560 us; speedup vs baseline: 7.0514x; 7.0514x over previous
//
#include <hip/hip_runtime.h>

#define NUM_CLASSES 26
#define SUBS 4                        // LDS sub-histograms per counter (round-2 proven layout)
#define NCOUNT (3 * NUM_CLASSES)      // 78 logical counters
#define LDSN (NCOUNT * SUBS)          // 312 LDS counters
#define NREP 16                       // global replica arrays (cut flush-atomic line contention)
#define REPSTRIDE 80                  // words between replicas (320 B -> distinct cache lines)
#define GC_WORDS (NREP * REPSTRIDE)   // 1280 words = 5 KB of d_ws
#define TPB 256

__global__ void sdl_zero(unsigned int* __restrict__ c) {
    for (int i = threadIdx.x; i < GC_WORDS; i += TPB) c[i] = 0u;
}

// LDS index = (hist*26+class)*SUBS + sub   (round-2 layout, measured 2.07M conflict cycles)
#define HIDX(hist, cls) ((((hist) * NUM_CLASSES) + (cls)) * SUBS + sub)
#define PROC_PAIR(aa, bb)                                                   \
    do {                                                                    \
        atomicAdd(&h[HIDX(0, (aa).x)], 1u);                                 \
        atomicAdd(&h[HIDX(0, (aa).y)], 1u);                                 \
        atomicAdd(&h[HIDX(0, (aa).z)], 1u);                                 \
        atomicAdd(&h[HIDX(0, (aa).w)], 1u);                                 \
        atomicAdd(&h[HIDX(1, (bb).x)], 1u);                                 \
        atomicAdd(&h[HIDX(1, (bb).y)], 1u);                                 \
        atomicAdd(&h[HIDX(1, (bb).z)], 1u);                                 \
        atomicAdd(&h[HIDX(1, (bb).w)], 1u);                                 \
        if ((aa).x == (bb).x) atomicAdd(&h[HIDX(2, (aa).x)], 1u);           \
        if ((aa).y == (bb).y) atomicAdd(&h[HIDX(2, (aa).y)], 1u);           \
        if ((aa).z == (bb).z) atomicAdd(&h[HIDX(2, (aa).z)], 1u);           \
        if ((aa).w == (bb).w) atomicAdd(&h[HIDX(2, (aa).w)], 1u);           \
    } while (0)

// __launch_bounds__(256, 2): allow up to ~256 VGPRs so the 16-int4 batch stays
// resident and all 16 dwordx4 loads are in flight (round-2's 44-VGPR codegen
// demoted the batch -> ~2 loads in flight -> latency-bound at 41 us).
__global__ __launch_bounds__(TPB, 2) void sdl_hist(
    const int4* __restrict__ f4, const int4* __restrict__ m4,
    unsigned int* __restrict__ gc, int n4, int nfull) {
    __shared__ unsigned int h[LDSN];
    for (int i = threadIdx.x; i < LDSN; i += TPB) h[i] = 0u;
    __syncthreads();

    const int tid      = blockIdx.x * TPB + threadIdx.x;
    const int nthreads = gridDim.x * TPB;
    const int sub      = threadIdx.x & (SUBS - 1);

    for (int base = tid; base < nfull; base += nthreads * 8) {
        int4 a[8], b[8];
        #pragma unroll
        for (int k = 0; k < 8; ++k) a[k] = f4[base + k * nthreads];
        #pragma unroll
        for (int k = 0; k < 8; ++k) b[k] = m4[base + k * nthreads];
        #pragma unroll
        for (int k = 0; k < 8; ++k) {
            int4 aa = a[k], bb = b[k];
            PROC_PAIR(aa, bb);
        }
    }
    for (int i = nfull + tid; i < n4; i += nthreads) {   // generic tail (empty here)
        int4 aa = f4[i], bb = m4[i];
        PROC_PAIR(aa, bb);
    }

    __syncthreads();
    // flush to one of 16 replica arrays: per-cache-line RMW contention / 16
    unsigned int* rep = gc + (blockIdx.x & (NREP - 1)) * REPSTRIDE;
    for (int i = threadIdx.x; i < NCOUNT; i += TPB) {
        unsigned int v = 0;
        #pragma unroll
        for (int s2 = 0; s2 < SUBS; ++s2) v += h[i * SUBS + s2];
        if (v) atomicAdd(&rep[i], v);
    }
}

__global__ void sdl_finalize(const unsigned int* __restrict__ gc,
                             float* __restrict__ out) {
    // kernel boundary provides device-scope visibility of hist's atomics
    __shared__ float vals[NCOUNT];
    if (threadIdx.x < NCOUNT) {
        unsigned int v = 0;
        for (int r = 0; r < NREP; ++r) v += gc[r * REPSTRIDE + threadIdx.x];
        vals[threadIdx.x] = (float)v;
    }
    __syncthreads();
    if (threadIdx.x == 0) {
        const float eps = 1e-5f;
        float s = 0.f;
        for (int c = 1; c < NUM_CLASSES; ++c) {
            float F = vals[c];
            float M = vals[NUM_CLASSES + c];
            float I = vals[2 * NUM_CLASSES + c];
            s += (2.f * I + eps) / (F + M + eps);
        }
        out[0] = 1.f - s / (float)(NUM_CLASSES - 1);
    }
}

extern "C" void kernel_launch(void* const* d_in, const int* in_sizes, int n_in,
                              void* d_out, int out_size, void* d_ws, size_t ws_size,
                              hipStream_t stream) {
    const int* f = (const int*)d_in[0];
    const int* m = (const int*)d_in[1];
    unsigned int* gc = (unsigned int*)d_ws;
    float* out = (float*)d_out;

    int n  = in_sizes[0];         // 14,155,776 (divisible by 4)
    int n4 = n / 4;               // 3,538,944 int4-pairs

    sdl_zero<<<1, TPB, 0, stream>>>(gc);

    int blocks = n4 / (TPB * 8);  // 1728: each thread exactly one 8-pair batch
    if (blocks < 1) blocks = 1;
    if (blocks > 4096) blocks = 4096;
    int nthreads = blocks * TPB;
    int nfull = (n4 / (nthreads * 8)) * (nthreads * 8);

    sdl_hist<<<blocks, TPB, 0, stream>>>((const int4*)f, (const int4*)m, gc, n4, nfull);

    sdl_finalize<<<1, 128, 0, stream>>>(gc, out);
}

// Round 6
// 30.670 us; speedup vs baseline: 7.2561x; 1.0290x over previous
//
#include <hip/hip_runtime.h>

#define NUM_CLASSES 26
#define NBINS (NUM_CLASSES * NUM_CLASSES)   // 676 pair bins
#define SUBS 2                              // LDS sub-histograms (sub-major layout)
#define LDSN (SUBS * NBINS)                 // 1352 words = 5.4 KB
#define NCOUNT (3 * NUM_CLASSES)            // 78 logical counters
#define NREP 16                             // global replica arrays for flush
#define REPSTRIDE 80                        // 320 B apart -> distinct cache lines
#define GC_WORDS (NREP * REPSTRIDE)         // 1280 words
#define TPB 256

__global__ void sdl_zero(unsigned int* __restrict__ c) {
    for (int i = threadIdx.x; i < GC_WORDS; i += TPB) c[i] = 0u;
}

// One ds_atomic per ELEMENT: pair bin idx = a*26 + b.
// F[c] = sum_b bin[c][b], M[c] = sum_a bin[a][c], I[c] = bin[c][c].
#define PROC_PAIR(aa, bb)                                                    \
    do {                                                                     \
        atomicAdd(&h[hb + ((aa).x * NUM_CLASSES + (bb).x)], 1u);             \
        atomicAdd(&h[hb + ((aa).y * NUM_CLASSES + (bb).y)], 1u);             \
        atomicAdd(&h[hb + ((aa).z * NUM_CLASSES + (bb).z)], 1u);             \
        atomicAdd(&h[hb + ((aa).w * NUM_CLASSES + (bb).w)], 1u);             \
    } while (0)

// launch_bounds(256,2): keep the 16-int4 batch resident (proven in R5; without
// it the allocator demotes the batch and loads serialize -> 41 us).
__global__ __launch_bounds__(TPB, 2) void sdl_hist(
    const int4* __restrict__ f4, const int4* __restrict__ m4,
    unsigned int* __restrict__ gc, int n4, int nfull) {
    __shared__ unsigned int h[LDSN];
    for (int i = threadIdx.x; i < LDSN; i += TPB) h[i] = 0u;
    __syncthreads();

    const int tid      = blockIdx.x * TPB + threadIdx.x;
    const int nthreads = gridDim.x * TPB;
    const int hb       = (threadIdx.x & (SUBS - 1)) * NBINS;  // sub-major base

    for (int base = tid; base < nfull; base += nthreads * 8) {
        int4 a[8], b[8];
        #pragma unroll
        for (int k = 0; k < 8; ++k) a[k] = f4[base + k * nthreads];
        #pragma unroll
        for (int k = 0; k < 8; ++k) b[k] = m4[base + k * nthreads];
        #pragma unroll
        for (int k = 0; k < 8; ++k) {
            int4 aa = a[k], bb = b[k];
            PROC_PAIR(aa, bb);
        }
    }
    for (int i = nfull + tid; i < n4; i += nthreads) {   // generic tail (empty here)
        int4 aa = f4[i], bb = m4[i];
        PROC_PAIR(aa, bb);
    }

    __syncthreads();

    // Per-block reduce 676-bin pair-hist -> 78 counters, flush to 1 of 16 replicas.
    unsigned int* rep = gc + (blockIdx.x & (NREP - 1)) * REPSTRIDE;
    const int t = threadIdx.x;
    if (t < NUM_CLASSES) {                         // wave 0: F[c] = row sum
        unsigned int v = 0;
        #pragma unroll
        for (int j = 0; j < NUM_CLASSES; ++j)
            v += h[t * NUM_CLASSES + j] + h[NBINS + t * NUM_CLASSES + j];
        if (v) atomicAdd(&rep[t], v);
    } else if (t >= 64 && t < 64 + NUM_CLASSES) {  // wave 1: M[c] = col sum
        int c = t - 64;
        unsigned int v = 0;
        #pragma unroll
        for (int j = 0; j < NUM_CLASSES; ++j)
            v += h[j * NUM_CLASSES + c] + h[NBINS + j * NUM_CLASSES + c];
        if (v) atomicAdd(&rep[NUM_CLASSES + c], v);
    } else if (t >= 128 && t < 128 + NUM_CLASSES) {  // wave 2: I[c] = diagonal
        int c = t - 128;
        unsigned int v = h[c * NUM_CLASSES + c] + h[NBINS + c * NUM_CLASSES + c];
        if (v) atomicAdd(&rep[2 * NUM_CLASSES + c], v);
    }
}

__global__ void sdl_finalize(const unsigned int* __restrict__ gc,
                             float* __restrict__ out) {
    // kernel boundary provides device-scope visibility of hist's atomics
    __shared__ float vals[NCOUNT];
    if (threadIdx.x < NCOUNT) {
        unsigned int v = 0;
        for (int r = 0; r < NREP; ++r) v += gc[r * REPSTRIDE + threadIdx.x];
        vals[threadIdx.x] = (float)v;
    }
    __syncthreads();
    if (threadIdx.x == 0) {
        const float eps = 1e-5f;
        float s = 0.f;
        for (int c = 1; c < NUM_CLASSES; ++c) {
            float F = vals[c];
            float M = vals[NUM_CLASSES + c];
            float I = vals[2 * NUM_CLASSES + c];
            s += (2.f * I + eps) / (F + M + eps);
        }
        out[0] = 1.f - s / (float)(NUM_CLASSES - 1);
    }
}

extern "C" void kernel_launch(void* const* d_in, const int* in_sizes, int n_in,
                              void* d_out, int out_size, void* d_ws, size_t ws_size,
                              hipStream_t stream) {
    const int* f = (const int*)d_in[0];
    const int* m = (const int*)d_in[1];
    unsigned int* gc = (unsigned int*)d_ws;
    float* out = (float*)d_out;

    int n  = in_sizes[0];         // 14,155,776 (divisible by 4)
    int n4 = n / 4;               // 3,538,944 int4-pairs

    sdl_zero<<<1, TPB, 0, stream>>>(gc);

    int blocks = n4 / (TPB * 8);  // 1728: each thread exactly one 8-pair batch
    if (blocks < 1) blocks = 1;
    if (blocks > 4096) blocks = 4096;
    int nthreads = blocks * TPB;
    int nfull = (n4 / (nthreads * 8)) * (nthreads * 8);

    sdl_hist<<<blocks, TPB, 0, stream>>>((const int4*)f, (const int4*)m, gc, n4, nfull);

    sdl_finalize<<<1, 128, 0, stream>>>(gc, out);
}